// Round 5
// baseline (557.892 us; speedup 1.0000x reference)
//
#include <hip/hip_runtime.h>
#include <math.h>

#define B 64
#define C 2048
#define FMH 14
#define HW 196       // 14*14
#define HW4 49       // HW / 4 (float4 columns)
#define CHUNKS 32
#define CPC (C / CHUNKS)   // 64 channels per chunk
#define NWIN 837
#define KMAX 6       // max windows per lane in a group (ceil(361/64))

// Per-ratio tables (RATIOS order from reference)
__device__ __constant__ int d_RH[11]   = {4, 3, 5, 6, 5, 7, 8, 6, 10, 7, 9};
__device__ __constant__ int d_RW[11]   = {4, 5, 3, 6, 7, 5, 8, 10, 6, 9, 7};
__device__ __constant__ int d_WOFF[12] = {0, 121, 241, 361, 442, 522, 602, 651, 696, 741, 789, 837};

__device__ inline void decode_box(int w, float& x0, float& y0, float& x1, float& y1, float& area) {
    int r = 0;
    while (w >= d_WOFF[r + 1]) ++r;
    int local = w - d_WOFF[r];
    int rh = d_RH[r], rw = d_RW[r];
    int wc = FMH - rw + 1;
    int i = local / wc, j = local - i * wc;
    x0 = (float)(j * 32);
    y0 = (float)(i * 32);
    x1 = (float)((j + rw) * 32 - 1);
    y1 = (float)((i + rh) * 32 - 1);
    area = (float)(rw * 32) * (float)(rh * 32);
}

// Fused kernel: 2048 blocks of 256. Phase A: block (chunk,b) reduces its 64
// channels into partial[b][chunk][196]. Last-arriving block per batch (agent-
// scope counter) becomes the tail: integral image + 837 scores + NMS, with the
// 3 NMS groups running on 3 independent waves (no barriers in NMS).
__global__ __launch_bounds__(256) void appm_fused_kernel(const float4* __restrict__ x,
                                                         float* __restrict__ partial,
                                                         int* __restrict__ cnt,
                                                         float* __restrict__ out) {
    const int chunk = blockIdx.x;
    const int b     = blockIdx.y;
    const int tid   = threadIdx.x;
    const int lane  = tid & 63;
    const int wave  = tid >> 6;

    // ---------- Phase A: channel-chunk reduction ----------
    float4 acc = make_float4(0.f, 0.f, 0.f, 0.f);
    if (lane < HW4) {
        const float4* base = x + (size_t)(b * C + chunk * CPC) * HW4 + lane;
        #pragma unroll
        for (int k = 0; k < CPC / 4; ++k) {   // 16 iters; channel = wave + 4*k
            float4 v = base[(size_t)(wave + 4 * k) * HW4];
            acc.x += v.x; acc.y += v.y; acc.z += v.z; acc.w += v.w;
        }
    }

    __shared__ float4 sh[256];
    sh[tid] = acc;
    __syncthreads();

    if (tid < 64 && lane < HW4) {
        float4 a0 = sh[lane], a1 = sh[64 + lane], a2 = sh[128 + lane], a3 = sh[192 + lane];
        float4 s;
        s.x = (a0.x + a1.x) + (a2.x + a3.x);
        s.y = (a0.y + a1.y) + (a2.y + a3.y);
        s.z = (a0.z + a1.z) + (a2.z + a3.z);
        s.w = (a0.w + a1.w) + (a2.w + a3.w);
        ((float4*)partial)[(size_t)(b * CHUNKS + chunk) * HW4 + lane] = s;
    }

    // ---------- Release + elect tail block ----------
    __syncthreads();
    __threadfence();                       // release our partial to agent scope
    __shared__ int s_last;
    if (tid == 0) {
        int old = __hip_atomic_fetch_add(&cnt[b], 1, __ATOMIC_ACQ_REL,
                                         __HIP_MEMORY_SCOPE_AGENT);
        s_last = (old == CHUNKS - 1) ? 1 : 0;
    }
    __syncthreads();
    if (!s_last) return;
    __threadfence();                       // acquire: invalidate stale cached lines

    // ---------- Phase B (tail block only): integral + scores + NMS ----------
    __shared__ float S[15][16];            // integral image, padded zero border
    __shared__ float sc[NWIN];

    const int ii = tid / FMH, jj = tid % FMH;
    if (tid < HW) {
        const float* p = partial + (size_t)b * CHUNKS * HW + tid;
        float a = 0.f;
        #pragma unroll
        for (int ch = 0; ch < CHUNKS; ++ch) a += p[(size_t)ch * HW];
        S[ii + 1][jj + 1] = a;
    }
    if (tid < 16) S[0][tid] = 0.f;
    if (tid < 15) S[tid][0] = 0.f;
    __syncthreads();

    // Hillis-Steele scans, 4 steps per direction
    #pragma unroll
    for (int s = 1; s < 14; s <<= 1) {
        float add = 0.f;
        if (tid < HW && jj >= s) add = S[ii + 1][jj + 1 - s];
        __syncthreads();
        if (tid < HW) S[ii + 1][jj + 1] += add;
        __syncthreads();
    }
    #pragma unroll
    for (int s = 1; s < 14; s <<= 1) {
        float add = 0.f;
        if (tid < HW && ii >= s) add = S[ii + 1 - s][jj + 1];
        __syncthreads();
        if (tid < HW) S[ii + 1][jj + 1] += add;
        __syncthreads();
    }

    // 837 window scores -> LDS + global all_scores
    for (int w = tid; w < NWIN; w += 256) {
        int r = 0;
        while (w >= d_WOFF[r + 1]) ++r;
        int local = w - d_WOFF[r];
        int rh = d_RH[r], rw = d_RW[r];
        int wc = FMH - rw + 1;
        int i = local / wc, j = local - i * wc;
        float s = (S[i + rh][j + rw] - S[i][j + rw] - S[i + rh][j] + S[i][j]) / (float)(rh * rw);
        sc[w] = s;
        out[768 + (size_t)b * NWIN + w] = s;
    }
    __syncthreads();

    // NMS: wave g handles group g (waves 0..2; wave 3 idle). Registers + shfl.
    const int g = wave;
    if (g >= 3) return;
    const int GOFFc[3] = {0, 361, 602};
    const int GWc[3]   = {361, 241, 235};
    const int NSELc[3] = {3, 2, 1};
    const int SLOTc[3] = {0, 3, 5};
    const int off = GOFFc[g], W = GWc[g];

    float sv[KMAX], bx0[KMAX], by0[KMAX], bx1[KMAX], by1[KMAX], bar[KMAX];
    unsigned vmask = 0;
    #pragma unroll
    for (int k = 0; k < KMAX; ++k) {
        int wl = lane + 64 * k;
        if (wl < W) {
            sv[k] = sc[off + wl];
            decode_box(off + wl, bx0[k], by0[k], bx1[k], by1[k], bar[k]);
            vmask |= (1u << k);
        } else {
            sv[k] = -INFINITY;
        }
    }

    int last = 0;
    const int nsel = NSELc[g];
    for (int it = 0; it < nsel; ++it) {
        float bv = -INFINITY; int bi = 0x7fffffff;
        #pragma unroll
        for (int k = 0; k < KMAX; ++k) {
            if (vmask & (1u << k)) {
                float v = sv[k];
                int wl = lane + 64 * k;
                if (v > bv || (v == bv && wl < bi)) { bv = v; bi = wl; }
            }
        }
        #pragma unroll
        for (int d = 1; d < 64; d <<= 1) {
            float ov = __shfl_xor(bv, d, 64);
            int   oi = __shfl_xor(bi, d, 64);
            if (ov > bv || (ov == bv && oi < bi)) { bv = ov; bi = oi; }
        }
        const bool any = (bv != -INFINITY);
        const int sel = any ? bi : last;
        last = sel;
        if (lane == 0) {
            out[(size_t)b * 6 + SLOTc[g] + it]       = (float)(off + sel);  // index
            out[384 + (size_t)b * 6 + SLOTc[g] + it] = sc[off + sel];       // score
        }
        if (any) {
            if (it + 1 < nsel) {
                float sx0, sy0, sx1, sy1, sa;
                decode_box(off + sel, sx0, sy0, sx1, sy1, sa);
                #pragma unroll
                for (int k = 0; k < KMAX; ++k) {
                    if (vmask & (1u << k)) {
                        float ltx = fmaxf(bx0[k], sx0), lty = fmaxf(by0[k], sy0);
                        float rbx = fminf(bx1[k], sx1), rby = fminf(by1[k], sy1);
                        float wx = rbx - ltx + 1.f, wy = rby - lty + 1.f;
                        float inter = (wx < 0.f || wy < 0.f) ? 0.f : wx * wy;
                        float iou = inter / (bar[k] + sa - inter);
                        if (iou > 0.25f) vmask &= ~(1u << k);
                    }
                }
            }
            if ((sel & 63) == lane) vmask &= ~(1u << (sel >> 6));
        }
    }
}

extern "C" void kernel_launch(void* const* d_in, const int* in_sizes, int n_in,
                              void* d_out, int out_size, void* d_ws, size_t ws_size,
                              hipStream_t stream) {
    const float* x = (const float*)d_in[0];
    float* out = (float*)d_out;
    float* partial = (float*)d_ws;                 // B*CHUNKS*HW floats = 1.6 MB
    int* cnt = (int*)((char*)d_ws + (size_t)B * CHUNKS * HW * sizeof(float));

    hipMemsetAsync(cnt, 0, B * sizeof(int), stream);   // ws is poisoned each call
    appm_fused_kernel<<<dim3(CHUNKS, B), 256, 0, stream>>>((const float4*)x, partial, cnt, out);
}

// Round 6
// 158.409 us; speedup vs baseline: 3.5218x; 3.5218x over previous
//
#include <hip/hip_runtime.h>
#include <math.h>

#define B 64
#define C 2048
#define FMH 14
#define HW 196       // 14*14
#define HW4 49       // HW / 4 (float4 columns)
#define CHUNKS 32
#define CPC (C / CHUNKS)   // 64 channels per chunk
#define NWIN 837
#define KMAX 6       // max windows per lane in a group (ceil(361/64))

// Per-ratio tables (RATIOS order from reference)
__device__ __constant__ int d_RH[11]   = {4, 3, 5, 6, 5, 7, 8, 6, 10, 7, 9};
__device__ __constant__ int d_RW[11]   = {4, 5, 3, 6, 7, 5, 8, 10, 6, 9, 7};
__device__ __constant__ int d_WOFF[12] = {0, 121, 241, 361, 442, 522, 602, 651, 696, 741, 789, 837};

// ---------------- Kernel 1: channel reduction ----------------
// x viewed as [B][C][49] float4; block (chunk, b) reduces CPC channels of one
// batch into partial[b][chunk][196]. Lane = float4 column (49 of 64 active).
// 4 independent accumulator chains + full unroll: all 16 loads issue before
// any dependent add -> 16 outstanding loads/wave (was ~4 with unroll-4 and a
// single serial accumulator chain). R5's fused version (per-block agent
// fences) stalled the TCCs -- never publish per-block data via device fences
// at this block count.
__global__ __launch_bounds__(256) void sum_channels_kernel(const float4* __restrict__ x,
                                                           float4* __restrict__ partial) {
    const int chunk = blockIdx.x;
    const int b     = blockIdx.y;
    const int lane  = threadIdx.x & 63;
    const int wave  = threadIdx.x >> 6;

    float4 a0 = make_float4(0.f, 0.f, 0.f, 0.f);
    float4 a1 = a0, a2 = a0, a3 = a0;
    if (lane < HW4) {
        const float4* base = x + (size_t)(b * C + chunk * CPC) * HW4 + lane;
        #pragma unroll
        for (int k = 0; k < CPC / 4; k += 4) {   // channel = wave + 4*(k+q)
            float4 v0 = base[(size_t)(wave + 4 * (k + 0)) * HW4];
            float4 v1 = base[(size_t)(wave + 4 * (k + 1)) * HW4];
            float4 v2 = base[(size_t)(wave + 4 * (k + 2)) * HW4];
            float4 v3 = base[(size_t)(wave + 4 * (k + 3)) * HW4];
            a0.x += v0.x; a0.y += v0.y; a0.z += v0.z; a0.w += v0.w;
            a1.x += v1.x; a1.y += v1.y; a1.z += v1.z; a1.w += v1.w;
            a2.x += v2.x; a2.y += v2.y; a2.z += v2.z; a2.w += v2.w;
            a3.x += v3.x; a3.y += v3.y; a3.z += v3.z; a3.w += v3.w;
        }
    }
    float4 acc;
    acc.x = (a0.x + a1.x) + (a2.x + a3.x);
    acc.y = (a0.y + a1.y) + (a2.y + a3.y);
    acc.z = (a0.z + a1.z) + (a2.z + a3.z);
    acc.w = (a0.w + a1.w) + (a2.w + a3.w);

    __shared__ float4 sh[256];
    sh[threadIdx.x] = acc;
    __syncthreads();

    if (threadIdx.x < 64 && lane < HW4) {
        float4 c0 = sh[lane], c1 = sh[64 + lane], c2 = sh[128 + lane], c3 = sh[192 + lane];
        float4 s;
        s.x = (c0.x + c1.x) + (c2.x + c3.x);
        s.y = (c0.y + c1.y) + (c2.y + c3.y);
        s.z = (c0.z + c1.z) + (c2.z + c3.z);
        s.w = (c0.w + c1.w) + (c2.w + c3.w);
        partial[(size_t)(b * CHUNKS + chunk) * HW4 + lane] = s;
    }
}

// ---------------- Kernel 2: one block per (group, batch) ----------------
__device__ inline void decode_box(int w, float& x0, float& y0, float& x1, float& y1, float& area) {
    int r = 0;
    while (w >= d_WOFF[r + 1]) ++r;
    int local = w - d_WOFF[r];
    int rh = d_RH[r], rw = d_RW[r];
    int wc = FMH - rw + 1;
    int i = local / wc, j = local - i * wc;
    x0 = (float)(j * 32);
    y0 = (float)(i * 32);
    x1 = (float)((j + rw) * 32 - 1);
    y1 = (float)((i + rh) * 32 - 1);
    area = (float)(rw * 32) * (float)(rh * 32);
}

__global__ __launch_bounds__(256) void scores_nms_kernel(const float* __restrict__ partial,
                                                         float* __restrict__ out) {
    const int g   = blockIdx.x;   // group 0..2
    const int b   = blockIdx.y;   // batch
    const int tid = threadIdx.x;

    __shared__ float S[15][16];   // integral image, padded zero border
    __shared__ float sc[361];     // this group's scores (max group width)

    // 1) y[hw] = sum over chunk partials (196 threads, coalesced 784B/wave)
    const int ii = tid / FMH, jj = tid % FMH;
    if (tid < HW) {
        const float* p = partial + (size_t)b * CHUNKS * HW + tid;
        float acc = 0.f;
        #pragma unroll
        for (int ch = 0; ch < CHUNKS; ++ch) acc += p[(size_t)ch * HW];
        S[ii + 1][jj + 1] = acc;
    }
    if (tid < 16) S[0][tid] = 0.f;
    if (tid < 15) S[tid][0] = 0.f;
    __syncthreads();

    // 2) integral image via Hillis-Steele scans (4 steps each direction)
    #pragma unroll
    for (int s = 1; s < 14; s <<= 1) {
        float add = 0.f;
        if (tid < HW && jj >= s) add = S[ii + 1][jj + 1 - s];
        __syncthreads();
        if (tid < HW) S[ii + 1][jj + 1] += add;
        __syncthreads();
    }
    #pragma unroll
    for (int s = 1; s < 14; s <<= 1) {
        float add = 0.f;
        if (tid < HW && ii >= s) add = S[ii + 1 - s][jj + 1];
        __syncthreads();
        if (tid < HW) S[ii + 1][jj + 1] += add;
        __syncthreads();
    }

    const int GOFFc[3] = {0, 361, 602};
    const int GWc[3]   = {361, 241, 235};
    const int NSELc[3] = {3, 2, 1};
    const int SLOTc[3] = {0, 3, 5};
    const int off = GOFFc[g], W = GWc[g];

    // 3) this group's window scores -> LDS (local idx) + global all_scores
    for (int wl = tid; wl < W; wl += 256) {
        int w = off + wl;
        int r = 0;
        while (w >= d_WOFF[r + 1]) ++r;
        int local = w - d_WOFF[r];
        int rh = d_RH[r], rw = d_RW[r];
        int wc = FMH - rw + 1;
        int i = local / wc, j = local - i * wc;
        float s = (S[i + rh][j + rw] - S[i][j + rw] - S[i + rh][j] + S[i][j]) / (float)(rh * rw);
        sc[wl] = s;
        out[768 + (size_t)b * NWIN + w] = s;
    }
    __syncthreads();

    // 4) greedy NMS for this group — wave 0 only, registers + shfl, no barriers
    if (tid >= 64) return;
    const int lane = tid;

    float sv[KMAX], bx0[KMAX], by0[KMAX], bx1[KMAX], by1[KMAX], bar[KMAX];
    unsigned vmask = 0;
    #pragma unroll
    for (int k = 0; k < KMAX; ++k) {
        int wl = lane + 64 * k;
        if (wl < W) {
            sv[k] = sc[wl];
            decode_box(off + wl, bx0[k], by0[k], bx1[k], by1[k], bar[k]);
            vmask |= (1u << k);
        } else {
            sv[k] = -INFINITY;
        }
    }

    int last = 0;
    const int nsel = NSELc[g];
    for (int it = 0; it < nsel; ++it) {
        float bv = -INFINITY; int bi = 0x7fffffff;
        #pragma unroll
        for (int k = 0; k < KMAX; ++k) {
            if (vmask & (1u << k)) {
                float v = sv[k];
                int wl = lane + 64 * k;
                if (v > bv || (v == bv && wl < bi)) { bv = v; bi = wl; }
            }
        }
        #pragma unroll
        for (int d = 1; d < 64; d <<= 1) {
            float ov = __shfl_xor(bv, d, 64);
            int   oi = __shfl_xor(bi, d, 64);
            if (ov > bv || (ov == bv && oi < bi)) { bv = ov; bi = oi; }
        }
        const bool any = (bv != -INFINITY);
        const int sel = any ? bi : last;
        last = sel;
        if (lane == 0) {
            out[(size_t)b * 6 + SLOTc[g] + it]       = (float)(off + sel);  // index
            out[384 + (size_t)b * 6 + SLOTc[g] + it] = sc[sel];             // score
        }
        if (any) {
            if (it + 1 < nsel) {
                float sx0, sy0, sx1, sy1, sa;
                decode_box(off + sel, sx0, sy0, sx1, sy1, sa);
                #pragma unroll
                for (int k = 0; k < KMAX; ++k) {
                    if (vmask & (1u << k)) {
                        float ltx = fmaxf(bx0[k], sx0), lty = fmaxf(by0[k], sy0);
                        float rbx = fminf(bx1[k], sx1), rby = fminf(by1[k], sy1);
                        float wx = rbx - ltx + 1.f, wy = rby - lty + 1.f;
                        float inter = (wx < 0.f || wy < 0.f) ? 0.f : wx * wy;
                        float iou = inter / (bar[k] + sa - inter);
                        if (iou > 0.25f) vmask &= ~(1u << k);
                    }
                }
            }
            if ((sel & 63) == lane) vmask &= ~(1u << (sel >> 6));
        }
    }
}

extern "C" void kernel_launch(void* const* d_in, const int* in_sizes, int n_in,
                              void* d_out, int out_size, void* d_ws, size_t ws_size,
                              hipStream_t stream) {
    const float* x = (const float*)d_in[0];
    float* out = (float*)d_out;
    float* partial = (float*)d_ws;   // B*CHUNKS*HW floats = 1.6 MB

    sum_channels_kernel<<<dim3(CHUNKS, B), 256, 0, stream>>>((const float4*)x, (float4*)partial);
    scores_nms_kernel<<<dim3(3, B), 256, 0, stream>>>(partial, out);
}